// Round 9
// baseline (238.437 us; speedup 1.0000x reference)
//
#include <hip/hip_runtime.h>
#include <math.h>

#define S_TOK 2048
#define NEXP  8
#define DDIM  768
#define HDIM  3072
#define KSEL  4096   // S * CAPACITY

typedef __attribute__((ext_vector_type(8))) short short8;
typedef __attribute__((ext_vector_type(4))) float f32x4;
typedef __attribute__((ext_vector_type(2))) unsigned int u32x2;

__device__ __forceinline__ unsigned short f2bf(float f) {
  unsigned u = __float_as_uint(f);
  u += 0x7fffu + ((u >> 16) & 1u);   // round-to-nearest-even
  return (unsigned short)(u >> 16);
}

__device__ __forceinline__ float gelu_fast(float v) {
  float u = 0.7978845608028654f * (v + 0.044715f * v * v * v);
  float t = __expf(-2.0f * fabsf(u));
  float th = (1.0f - t) / (1.0f + t);
  th = copysignf(th, u);
  return 0.5f * v * (1.0f + th);
}

__global__ __launch_bounds__(256) void zero_kernel(float* __restrict__ p, int n) {
  int i = blockIdx.x * 256 + threadIdx.x;
  if (i < n) p[i] = 0.f;
}

__global__ __launch_bounds__(256) void convx_kernel(const float* __restrict__ x,
                                                    short* __restrict__ xb) {
  int i = (blockIdx.x * 256 + threadIdx.x) * 8;
  float4 a = *(const float4*)(x + i);
  float4 b = *(const float4*)(x + i + 4);
  short8 v;
  v[0] = (short)f2bf(a.x); v[1] = (short)f2bf(a.y);
  v[2] = (short)f2bf(a.z); v[3] = (short)f2bf(a.w);
  v[4] = (short)f2bf(b.x); v[5] = (short)f2bf(b.y);
  v[6] = (short)f2bf(b.z); v[7] = (short)f2bf(b.w);
  *(short8*)(xb + i) = v;
}

// ---------------- K1: gating (logits + softmax), exact fp32 ----------------
__global__ __launch_bounds__(256) void gate_kernel(
    const float* __restrict__ x, const float* __restrict__ gw,
    float* __restrict__ scores)
{
  int tid  = threadIdx.x;
  int lane = tid & 63;
  int wid  = tid >> 6;
  int token = blockIdx.x * 4 + wid;
  const float* xr = x + (size_t)token * DDIM;

  float acc[NEXP];
#pragma unroll
  for (int e = 0; e < NEXP; ++e) acc[e] = 0.f;

  for (int d = lane; d < DDIM; d += 64) {
    float xv = xr[d];
#pragma unroll
    for (int e = 0; e < NEXP; ++e) acc[e] += xv * gw[e * DDIM + d];
  }
#pragma unroll
  for (int e = 0; e < NEXP; ++e) {
    for (int off = 32; off; off >>= 1) acc[e] += __shfl_down(acc[e], off, 64);
  }
  if (lane == 0) {
    float m = acc[0];
#pragma unroll
    for (int e = 1; e < NEXP; ++e) m = fmaxf(m, acc[e]);
    float p[NEXP], s = 0.f;
#pragma unroll
    for (int e = 0; e < NEXP; ++e) { p[e] = expf(acc[e] - m); s += p[e]; }
    float inv = 1.0f / s;
#pragma unroll
    for (int e = 0; e < NEXP; ++e) scores[e * S_TOK + token] = p[e] * inv;
  }
}

// ---------------- K2: exact global top-k selection ----------------
__device__ unsigned block_scan_excl(unsigned v, volatile unsigned* wsum) {
  int tid = threadIdx.x, lane = tid & 63, wid = tid >> 6;
  __syncthreads();
  unsigned x = v;
#pragma unroll
  for (int off = 1; off < 64; off <<= 1) {
    unsigned t = __shfl_up(x, off, 64);
    if (lane >= off) x += t;
  }
  if (lane == 63) wsum[wid] = x;
  __syncthreads();
  if (tid < 64) {
    unsigned w = (lane < 16) ? wsum[lane] : 0u;
#pragma unroll
    for (int off = 1; off < 16; off <<= 1) {
      unsigned t = __shfl_up(w, off, 64);
      if (lane >= off) w += t;
    }
    if (lane < 16) wsum[lane] = w;
  }
  __syncthreads();
  unsigned woff = (wid > 0) ? wsum[wid - 1] : 0u;
  return woff + (x - v);
}

__global__ __launch_bounds__(1024) void select_kernel(
    const float* __restrict__ scores,
    int* __restrict__ tokenlist, float* __restrict__ slotgate,
    int* __restrict__ offsets)
{
  __shared__ unsigned cnt;
  __shared__ unsigned wsum[16];
  int tid = threadIdx.x;
  int base = tid * 16;

  float sv[16]; unsigned key[16];
#pragma unroll
  for (int j = 0; j < 16; ++j) {
    sv[j] = scores[base + j];
    key[j] = __float_as_uint(sv[j]);
  }

  unsigned lo = 0, hi = 0x3F800000u;
  while (lo < hi) {
    unsigned mid = lo + ((hi - lo + 1) >> 1);
    if (tid == 0) cnt = 0;
    __syncthreads();
    unsigned c = 0;
#pragma unroll
    for (int j = 0; j < 16; ++j) c += (key[j] >= mid) ? 1u : 0u;
    for (int off = 32; off; off >>= 1) c += __shfl_down(c, off, 64);
    if ((tid & 63) == 0) atomicAdd(&cnt, c);
    __syncthreads();
    unsigned tot = cnt;
    __syncthreads();
    if (tot >= (unsigned)KSEL) lo = mid; else hi = mid - 1;
  }
  unsigned V = lo;

  if (tid == 0) cnt = 0;
  __syncthreads();
  {
    unsigned c = 0;
#pragma unroll
    for (int j = 0; j < 16; ++j) c += (key[j] > V) ? 1u : 0u;
    for (int off = 32; off; off >>= 1) c += __shfl_down(c, off, 64);
    if ((tid & 63) == 0) atomicAdd(&cnt, c);
  }
  __syncthreads();
  int need = KSEL - (int)cnt;
  __syncthreads();

  unsigned tloc = 0;
#pragma unroll
  for (int j = 0; j < 16; ++j) tloc += (key[j] == V) ? 1u : 0u;
  unsigned texcl = block_scan_excl(tloc, wsum);

  unsigned selmask = 0, sloc = 0, trun = texcl;
#pragma unroll
  for (int j = 0; j < 16; ++j) {
    bool f;
    if (key[j] > V) f = true;
    else if (key[j] == V) { f = ((int)trun < need); ++trun; }
    else f = false;
    if (f) { selmask |= (1u << j); ++sloc; }
  }
  unsigned sexcl = block_scan_excl(sloc, wsum);

  // expert e starts at flat index e*2048 == thread e*128
  if ((tid & 127) == 0) offsets[tid >> 7] = (int)sexcl;
  if (tid == 0) offsets[NEXP] = KSEL;

  unsigned p = sexcl;
#pragma unroll
  for (int j = 0; j < 16; ++j) {
    int i = base + j;
    if (selmask & (1u << j)) {
      tokenlist[p] = i & (S_TOK - 1);
      slotgate[p] = sv[j];
      ++p;
    }
  }
}

// ------- K3/K4: bf16 MFMA grouped GEMM, 128x64 tile, 2 waves, BK=32 -------
// Proven tr layout: B tiles [kq(8)][ng(4)] contiguous 128B, vaddr=tile*128+l15*8,
// pair read at offset:512 (+4 tiles = next kq). Conflict-free staging maps.
// grid = (expert=8, N/64, slots) -> linear_id % 8 == expert (XCD affinity)
// MODE 1: z=tile(16);            A = xbf gathered (K=768); hbuf = gelu(A@W1+b1), bf16
// MODE 2: z=tile(16)*4+split(4); A = hbuf (K=3072/4);      y[token] += gate*(A@W2+b2)
template <int MODE>
__global__ __launch_bounds__(128) void moe_mfma(
    const short* __restrict__ Abase, const float* __restrict__ W,
    const float* __restrict__ bias, void* __restrict__ outp,
    const int* __restrict__ offsets, const int* __restrict__ tokenlist,
    const float* __restrict__ slotgate)
{
  const int e = (int)blockIdx.x;
  const int K = (MODE == 1) ? DDIM : HDIM;
  const int N = (MODE == 1) ? HDIM : DDIM;
  const int tile  = (MODE == 1) ? (int)blockIdx.z : ((int)blockIdx.z >> 2);
  const int split = (MODE == 1) ? 0 : ((int)blockIdx.z & 3);
  const int klen  = 768;                  // DDIM and HDIM/4
  const int kb = split * klen;

  const int r0 = offsets[e];
  const int rows = offsets[e + 1] - r0;
  const int rowbase = tile << 7;
  if (rowbase >= rows) return;
  int vr = rows - rowbase; if (vr > 128) vr = 128;
  const int colbase = (int)blockIdx.y << 6;   // 64-col tiles

  __shared__ short As[128 * 40];                // 10240 B, [row][40-padded k]
  __shared__ __align__(16) short Bs[32 * 64];   // 4096 B, 32 tiles (kq*4+ng)*128B
  const unsigned bs_lds = (unsigned)(uintptr_t)&Bs[0];

  const int tid = threadIdx.x;                  // 0..127
  const int lane = tid & 63;
  const int wid = tid >> 6;
  const int wr = wid << 6;                      // wave rows: 0 / 64
  const int l15 = lane & 15;
  const int lq = lane >> 4;

  // A staging: one row per thread (128 rows), 32 k = 4 short8 per step
  const short* arow;
  {
    int cr = (tid < vr) ? tid : (vr - 1);
    if (MODE == 1) arow = Abase + (size_t)tokenlist[r0 + rowbase + cr] * DDIM;
    else           arow = Abase + (size_t)(r0 + rowbase + cr) * HDIM + kb;
  }

  // B staging: thread t -> k-row (t>>2), col group (t&3)*4, q in 0..3 -> ng=q
  const int brow = tid >> 2;
  const int bc4 = tid & 3;
  const float* wsrc = W + (size_t)e * K * N + (size_t)kb * N + colbase + bc4 * 4;
  // LDS write base (bytes): tile(kq=tid>>4, ng=q)*128 + (brow&3)*32 + bc4*8
  const int bwbase = ((tid >> 4) << 9) + ((brow & 3) << 5) + (bc4 << 3);

  f32x4 acc[4][4];
#pragma unroll
  for (int i = 0; i < 4; ++i)
#pragma unroll
    for (int j = 0; j < 4; ++j) acc[i][j] = (f32x4){0.f, 0.f, 0.f, 0.f};

  short8 av[4];
  float4 bw[4];

#define LOAD_AB(KN)                                              \
  {                                                              \
    _Pragma("unroll")                                            \
    for (int m = 0; m < 4; ++m)                                  \
      av[m] = *(const short8*)(arow + (KN) + m * 8);             \
    const float* wp = wsrc + (size_t)((KN) + brow) * N;          \
    _Pragma("unroll")                                            \
    for (int q = 0; q < 4; ++q) bw[q] = *(const float4*)(wp + q * 16); \
  }

#define WRITE_LDS()                                              \
  {                                                              \
    _Pragma("unroll")                                            \
    for (int m = 0; m < 4; ++m)                                  \
      *(short8*)&As[tid * 40 + m * 8] = av[m];                   \
    _Pragma("unroll")                                            \
    for (int q = 0; q < 4; ++q) {                                \
      u32x2 pk;                                                  \
      pk[0] = (unsigned)f2bf(bw[q].x) | ((unsigned)f2bf(bw[q].y) << 16); \
      pk[1] = (unsigned)f2bf(bw[q].z) | ((unsigned)f2bf(bw[q].w) << 16); \
      *(u32x2*)((char*)Bs + bwbase + (q << 7)) = pk;             \
    }                                                            \
  }

  // prologue
  LOAD_AB(0);

#pragma unroll 1
  for (int k0 = 0; k0 < klen; k0 += 32) {
    __syncthreads();
    WRITE_LDS();
    __syncthreads();
    if (k0 + 32 < klen) LOAD_AB(k0 + 32);
    // fragments
    short8 af[4], bfr[4];
#pragma unroll
    for (int i = 0; i < 4; ++i)
      af[i] = *(const short8*)&As[(wr + i * 16 + l15) * 40 + lq * 8];
#pragma unroll
    for (int j = 0; j < 4; ++j) {
      // first tile: kq=2*lq, ng=j -> (8*lq + j)*128; pair at +512 (kq=2*lq+1)
      unsigned off = bs_lds + ((unsigned)(8 * lq + j) << 7) + ((unsigned)l15 << 3);
      union { short8 s; u32x2 u[2]; } fb;
      asm volatile("ds_read_b64_tr_b16 %0, %2 offset:0\n\t"
                   "ds_read_b64_tr_b16 %1, %2 offset:512"
                   : "=&v"(fb.u[0]), "=&v"(fb.u[1]) : "v"(off));
      bfr[j] = fb.s;
    }
    asm volatile("s_waitcnt lgkmcnt(0)" ::: "memory");
    __builtin_amdgcn_sched_barrier(0);
#pragma unroll
    for (int i = 0; i < 4; ++i)
#pragma unroll
      for (int j = 0; j < 4; ++j)
        acc[i][j] = __builtin_amdgcn_mfma_f32_16x16x32_bf16(af[i], bfr[j], acc[i][j], 0, 0, 0);
  }

  if (MODE == 1) {
    short* hb = (short*)outp;
    const float* bp = bias + (size_t)e * N + colbase;
#pragma unroll
    for (int i = 0; i < 4; ++i) {
      int rb = wr + i * 16 + lq * 4;
#pragma unroll
      for (int j = 0; j < 4; ++j) {
        int col = j * 16 + l15;
        float bvv = bp[col];
#pragma unroll
        for (int p = 0; p < 4; ++p) {
          int r = rb + p;
          if (r < vr)
            hb[(size_t)(r0 + rowbase + r) * HDIM + colbase + col] =
                (short)f2bf(gelu_fast(acc[i][j][p] + bvv));
        }
      }
    }
  } else {
    float* y = (float*)outp;
    const float* bp = bias + (size_t)e * N + colbase;
#pragma unroll
    for (int i = 0; i < 4; ++i) {
      int rb = wr + i * 16 + lq * 4;
#pragma unroll
      for (int p = 0; p < 4; ++p) {
        int r = rb + p;
        if (r < vr) {
          int gi = r0 + rowbase + r;
          float g = slotgate[gi];
          float* yrow = y + (size_t)tokenlist[gi] * N + colbase;
#pragma unroll
          for (int j = 0; j < 4; ++j) {
            int col = j * 16 + l15;
            float v = acc[i][j][p] + (split == 0 ? bp[col] : 0.f);
            atomicAdd(&yrow[col], g * v);
          }
        }
      }
    }
  }
}

extern "C" void kernel_launch(void* const* d_in, const int* in_sizes, int n_in,
                              void* d_out, int out_size, void* d_ws, size_t ws_size,
                              hipStream_t stream) {
  const float* x  = (const float*)d_in[0];
  const float* gw = (const float*)d_in[1];
  const float* w1 = (const float*)d_in[2];
  const float* b1 = (const float*)d_in[3];
  const float* w2 = (const float*)d_in[4];
  const float* b2 = (const float*)d_in[5];
  float* y = (float*)d_out;

  char* ws = (char*)d_ws;
  float* scores    = (float*)(ws);                    // 64 KB
  int*   tokenlist = (int*)(ws + (64 << 10));         // 16 KB
  float* slotgate  = (float*)(ws + (80 << 10));       // 16 KB
  int*   offsets   = (int*)(ws + (96 << 10));         // 9 ints
  short* xbf       = (short*)(ws + (128 << 10));      // 3 MB
  short* hbuf      = (short*)(ws + (128 << 10) + (size_t)S_TOK * DDIM * 2);  // 24 MB

  zero_kernel<<<(out_size + 255) / 256, 256, 0, stream>>>(y, out_size);
  convx_kernel<<<S_TOK * DDIM / 2048, 256, 0, stream>>>(x, xbf);
  gate_kernel<<<S_TOK / 4, 256, 0, stream>>>(x, gw, scores);
  select_kernel<<<1, 1024, 0, stream>>>(scores, tokenlist, slotgate, offsets);

  dim3 g1(NEXP, HDIM / 64, 16);    // expert fastest -> id%8 == expert (XCD affinity)
  moe_mfma<1><<<g1, 128, 0, stream>>>(xbf, w1, b1, hbuf, offsets, tokenlist, slotgate);
  dim3 g2(NEXP, DDIM / 64, 64);    // z = tile*4 + ksplit
  moe_mfma<2><<<g2, 128, 0, stream>>>(hbuf, w2, b2, y, offsets, tokenlist, slotgate);
}

// Round 10
// 197.267 us; speedup vs baseline: 1.2087x; 1.2087x over previous
//
#include <hip/hip_runtime.h>
#include <math.h>

#define S_TOK 2048
#define NEXP  8
#define DDIM  768
#define HDIM  3072
#define KSEL  4096   // S * CAPACITY

typedef __attribute__((ext_vector_type(8))) short short8;
typedef __attribute__((ext_vector_type(4))) float f32x4;
typedef __attribute__((ext_vector_type(2))) unsigned int u32x2;

__device__ __forceinline__ unsigned short f2bf(float f) {
  unsigned u = __float_as_uint(f);
  u += 0x7fffu + ((u >> 16) & 1u);   // round-to-nearest-even
  return (unsigned short)(u >> 16);
}

__device__ __forceinline__ float gelu_fast(float v) {
  float u = 0.7978845608028654f * (v + 0.044715f * v * v * v);
  float t = __expf(-2.0f * fabsf(u));
  float th = (1.0f - t) / (1.0f + t);
  th = copysignf(th, u);
  return 0.5f * v * (1.0f + th);
}

__global__ __launch_bounds__(256) void convx_kernel(const float* __restrict__ x,
                                                    short* __restrict__ xb) {
  int i = (blockIdx.x * 256 + threadIdx.x) * 8;
  float4 a = *(const float4*)(x + i);
  float4 b = *(const float4*)(x + i + 4);
  short8 v;
  v[0] = (short)f2bf(a.x); v[1] = (short)f2bf(a.y);
  v[2] = (short)f2bf(a.z); v[3] = (short)f2bf(a.w);
  v[4] = (short)f2bf(b.x); v[5] = (short)f2bf(b.y);
  v[6] = (short)f2bf(b.z); v[7] = (short)f2bf(b.w);
  *(short8*)(xb + i) = v;
}

// ---------------- K1: gating (logits + softmax), exact fp32 ----------------
__global__ __launch_bounds__(256) void gate_kernel(
    const float* __restrict__ x, const float* __restrict__ gw,
    float* __restrict__ scores)
{
  int tid  = threadIdx.x;
  int lane = tid & 63;
  int wid  = tid >> 6;
  int token = blockIdx.x * 4 + wid;
  const float* xr = x + (size_t)token * DDIM;

  float acc[NEXP];
#pragma unroll
  for (int e = 0; e < NEXP; ++e) acc[e] = 0.f;

  for (int d = lane; d < DDIM; d += 64) {
    float xv = xr[d];
#pragma unroll
    for (int e = 0; e < NEXP; ++e) acc[e] += xv * gw[e * DDIM + d];
  }
#pragma unroll
  for (int e = 0; e < NEXP; ++e) {
    for (int off = 32; off; off >>= 1) acc[e] += __shfl_down(acc[e], off, 64);
  }
  if (lane == 0) {
    float m = acc[0];
#pragma unroll
    for (int e = 1; e < NEXP; ++e) m = fmaxf(m, acc[e]);
    float p[NEXP], s = 0.f;
#pragma unroll
    for (int e = 0; e < NEXP; ++e) { p[e] = expf(acc[e] - m); s += p[e]; }
    float inv = 1.0f / s;
#pragma unroll
    for (int e = 0; e < NEXP; ++e) scores[e * S_TOK + token] = p[e] * inv;
  }
}

// ---------------- K2: exact global top-k selection ----------------
__device__ unsigned block_scan_excl(unsigned v, volatile unsigned* wsum) {
  int tid = threadIdx.x, lane = tid & 63, wid = tid >> 6;
  __syncthreads();
  unsigned x = v;
#pragma unroll
  for (int off = 1; off < 64; off <<= 1) {
    unsigned t = __shfl_up(x, off, 64);
    if (lane >= off) x += t;
  }
  if (lane == 63) wsum[wid] = x;
  __syncthreads();
  if (tid < 64) {
    unsigned w = (lane < 16) ? wsum[lane] : 0u;
#pragma unroll
    for (int off = 1; off < 16; off <<= 1) {
      unsigned t = __shfl_up(w, off, 64);
      if (lane >= off) w += t;
    }
    if (lane < 16) wsum[lane] = w;
  }
  __syncthreads();
  unsigned woff = (wid > 0) ? wsum[wid - 1] : 0u;
  return woff + (x - v);
}

__global__ __launch_bounds__(1024) void select_kernel(
    const float* __restrict__ scores,
    int* __restrict__ tokenlist, float* __restrict__ slotgate,
    int* __restrict__ offsets, int* __restrict__ posmap)
{
  __shared__ unsigned cnt;
  __shared__ unsigned wsum[16];
  int tid = threadIdx.x;
  int base = tid * 16;

  float sv[16]; unsigned key[16];
#pragma unroll
  for (int j = 0; j < 16; ++j) {
    sv[j] = scores[base + j];
    key[j] = __float_as_uint(sv[j]);
  }

  unsigned lo = 0, hi = 0x3F800000u;
  while (lo < hi) {
    unsigned mid = lo + ((hi - lo + 1) >> 1);
    if (tid == 0) cnt = 0;
    __syncthreads();
    unsigned c = 0;
#pragma unroll
    for (int j = 0; j < 16; ++j) c += (key[j] >= mid) ? 1u : 0u;
    for (int off = 32; off; off >>= 1) c += __shfl_down(c, off, 64);
    if ((tid & 63) == 0) atomicAdd(&cnt, c);
    __syncthreads();
    unsigned tot = cnt;
    __syncthreads();
    if (tot >= (unsigned)KSEL) lo = mid; else hi = mid - 1;
  }
  unsigned V = lo;

  if (tid == 0) cnt = 0;
  __syncthreads();
  {
    unsigned c = 0;
#pragma unroll
    for (int j = 0; j < 16; ++j) c += (key[j] > V) ? 1u : 0u;
    for (int off = 32; off; off >>= 1) c += __shfl_down(c, off, 64);
    if ((tid & 63) == 0) atomicAdd(&cnt, c);
  }
  __syncthreads();
  int need = KSEL - (int)cnt;
  __syncthreads();

  unsigned tloc = 0;
#pragma unroll
  for (int j = 0; j < 16; ++j) tloc += (key[j] == V) ? 1u : 0u;
  unsigned texcl = block_scan_excl(tloc, wsum);

  unsigned selmask = 0, sloc = 0, trun = texcl;
#pragma unroll
  for (int j = 0; j < 16; ++j) {
    bool f;
    if (key[j] > V) f = true;
    else if (key[j] == V) { f = ((int)trun < need); ++trun; }
    else f = false;
    if (f) { selmask |= (1u << j); ++sloc; }
  }
  unsigned sexcl = block_scan_excl(sloc, wsum);

  // expert e starts at flat index e*2048 == thread e*128
  if ((tid & 127) == 0) offsets[tid >> 7] = (int)sexcl;
  if (tid == 0) offsets[NEXP] = KSEL;

  unsigned p = sexcl;
#pragma unroll
  for (int j = 0; j < 16; ++j) {
    int i = base + j;
    if (selmask & (1u << j)) {
      posmap[i] = (int)p;
      tokenlist[p] = i & (S_TOK - 1);
      slotgate[p] = sv[j];
      ++p;
    } else {
      posmap[i] = -1;
    }
  }
}

// ------- K3/K4: bf16 MFMA grouped GEMM, 128x128 tile, BK=32 -------
// R6-proven layouts (A pad-40; B 128B 4x16 tiles, tr-read pair offset:1024),
// R8-proven schedule: double-buffered LDS, frags->lgkm fence->MFMA, THEN write
// next buffer (its vmcnt wait lands after the MFMAs); prefetch distance 2 steps.
// grid = (expert=8, N/128, slots) -> linear_id % 8 == expert (XCD affinity)
// MODE 1: z=tile(16);            A = xbf gathered (K=768); hbuf = gelu(A@W1+b1), bf16
// MODE 2: z=tile(16)*2+split(2); A = hbuf (K=3072/2);      outbuf[split] = A@W2 (+b2 on split0)
template <int MODE>
__global__ __launch_bounds__(256) void moe_mfma(
    const short* __restrict__ Abase, const float* __restrict__ W,
    const float* __restrict__ bias, void* __restrict__ outp,
    const int* __restrict__ offsets, const int* __restrict__ tokenlist)
{
  const int e = (int)blockIdx.x;
  const int K = (MODE == 1) ? DDIM : HDIM;
  const int N = (MODE == 1) ? HDIM : DDIM;
  const int tile  = (MODE == 1) ? (int)blockIdx.z : ((int)blockIdx.z >> 1);
  const int split = (MODE == 1) ? 0 : ((int)blockIdx.z & 1);
  const int klen  = (MODE == 1) ? DDIM : (HDIM / 2);
  const int kb = split * klen;

  const int r0 = offsets[e];
  const int rows = offsets[e + 1] - r0;
  const int rowbase = tile << 7;
  if (rowbase >= rows) return;
  int vr = rows - rowbase; if (vr > 128) vr = 128;
  const int colbase = (int)blockIdx.y << 7;

  __shared__ short As0[128 * 40];                 // 10240 B each
  __shared__ short As1[128 * 40];
  __shared__ __align__(16) short Bs0[32 * 128];   // 8192 B each, 64 tiles of 4x16
  __shared__ __align__(16) short Bs1[32 * 128];
  const unsigned bs0_lds = (unsigned)(uintptr_t)&Bs0[0];
  const unsigned bs1_lds = (unsigned)(uintptr_t)&Bs1[0];

  const int tid = threadIdx.x;
  const int lane = tid & 63;
  const int wid = tid >> 6;
  const int wr = (wid >> 1) << 6;
  const int wc = (wid & 1) << 6;
  const int l15 = lane & 15;
  const int lq = lane >> 4;

  // A staging: row ar = tid>>1, k-offset ak = (tid&1)*16
  const int ar = tid >> 1;
  const int ak = (tid & 1) << 4;
  const short* arow;
  {
    int cr = (ar < vr) ? ar : (vr - 1);
    if (MODE == 1) arow = Abase + (size_t)tokenlist[r0 + rowbase + cr] * DDIM;
    else           arow = Abase + (size_t)(r0 + rowbase + cr) * HDIM + kb;
  }

  // B staging: k-row sk = tid>>3, n-group g8 = tid&7 (16 cols = 4 float4s)
  const int sk = tid >> 3;
  const int g8 = tid & 7;
  const float* wsrc = W + (size_t)e * K * N + (size_t)kb * N + colbase + g8 * 16;
  // LDS write base (shorts): tile (kq=sk>>2, ng=g8)*64 + row(sk&3)*16
  const int bwoff = ((((sk >> 2) << 3) + g8) << 6) + ((sk & 3) << 4);

  f32x4 acc[4][4];
#pragma unroll
  for (int i = 0; i < 4; ++i)
#pragma unroll
    for (int j = 0; j < 4; ++j) acc[i][j] = (f32x4){0.f, 0.f, 0.f, 0.f};

  short8 avP0, avP1, avQ0, avQ1;
  float4 bwP[4], bwQ[4];

#define LOAD_AB(A0, A1, BW, KN)                                  \
  {                                                              \
    A0 = *(const short8*)(arow + (KN) + ak);                     \
    A1 = *(const short8*)(arow + (KN) + ak + 8);                 \
    const float* wp = wsrc + (size_t)((KN) + sk) * N;            \
    _Pragma("unroll")                                            \
    for (int q = 0; q < 4; ++q) BW[q] = *(const float4*)(wp + 4 * q); \
  }

#define WRITE_LDS(A0, A1, BW, AS, BS)                            \
  {                                                              \
    *(short8*)&AS[ar * 40 + ak] = A0;                            \
    *(short8*)&AS[ar * 40 + ak + 8] = A1;                        \
    _Pragma("unroll")                                            \
    for (int q = 0; q < 4; ++q) {                                \
      u32x2 pk;                                                  \
      pk[0] = (unsigned)f2bf(BW[q].x) | ((unsigned)f2bf(BW[q].y) << 16); \
      pk[1] = (unsigned)f2bf(BW[q].z) | ((unsigned)f2bf(BW[q].w) << 16); \
      *(u32x2*)((short*)BS + bwoff + 4 * q) = pk;                \
    }                                                            \
  }

#define FRAGS_MFMA(AS, BLDS)                                     \
  {                                                              \
    short8 af[4], bfr[4];                                        \
    _Pragma("unroll")                                            \
    for (int i = 0; i < 4; ++i)                                  \
      af[i] = *(const short8*)&AS[(wr + i * 16 + l15) * 40 + lq * 8]; \
    _Pragma("unroll")                                            \
    for (int j = 0; j < 4; ++j) {                                \
      unsigned off = (BLDS) + ((unsigned)((lq << 4) + (wc >> 4) + j) << 7) + \
                     ((unsigned)l15 << 3);                       \
      union { short8 s; u32x2 u[2]; } fb;                        \
      asm volatile("ds_read_b64_tr_b16 %0, %2 offset:0\n\t"      \
                   "ds_read_b64_tr_b16 %1, %2 offset:1024"       \
                   : "=&v"(fb.u[0]), "=&v"(fb.u[1]) : "v"(off)); \
      bfr[j] = fb.s;                                             \
    }                                                            \
    asm volatile("s_waitcnt lgkmcnt(0)" ::: "memory");           \
    __builtin_amdgcn_sched_barrier(0);                           \
    _Pragma("unroll")                                            \
    for (int i = 0; i < 4; ++i)                                  \
      _Pragma("unroll")                                          \
      for (int j = 0; j < 4; ++j)                                \
        acc[i][j] = __builtin_amdgcn_mfma_f32_16x16x32_bf16(af[i], bfr[j], acc[i][j], 0, 0, 0); \
  }

  // prologue: P=step0 -> buf0; Q=step1 staged in regs
  LOAD_AB(avP0, avP1, bwP, 0);
  WRITE_LDS(avP0, avP1, bwP, As0, Bs0);
  LOAD_AB(avQ0, avQ1, bwQ, 32);
  __syncthreads();

#pragma unroll 1
  for (int k0 = 0; k0 < klen; k0 += 64) {
    // step A: issue P=@k0+64; consume buf0 (@k0); write Q(@k0+32)->buf1
    if (k0 + 64 < klen) LOAD_AB(avP0, avP1, bwP, k0 + 64);
    FRAGS_MFMA(As0, bs0_lds);
    WRITE_LDS(avQ0, avQ1, bwQ, As1, Bs1);
    __syncthreads();
    // step B: issue Q=@k0+96; consume buf1 (@k0+32); write P(@k0+64)->buf0
    if (k0 + 96 < klen) LOAD_AB(avQ0, avQ1, bwQ, k0 + 96);
    FRAGS_MFMA(As1, bs1_lds);
    if (k0 + 64 < klen) { WRITE_LDS(avP0, avP1, bwP, As0, Bs0); }
    __syncthreads();
  }

  if (MODE == 1) {
    short* hb = (short*)outp;
    const float* bp = bias + (size_t)e * N + colbase;
#pragma unroll
    for (int i = 0; i < 4; ++i) {
      int rb = wr + i * 16 + lq * 4;
#pragma unroll
      for (int j = 0; j < 4; ++j) {
        int col = wc + j * 16 + l15;
        float bvv = bp[col];
#pragma unroll
        for (int p = 0; p < 4; ++p) {
          int r = rb + p;
          if (r < vr)
            hb[(size_t)(r0 + rowbase + r) * HDIM + colbase + col] =
                (short)f2bf(gelu_fast(acc[i][j][p] + bvv));
        }
      }
    }
  } else {
    float* ob = (float*)outp + (size_t)split * KSEL * DDIM;
    const float* bp = bias + (size_t)e * N + colbase;
#pragma unroll
    for (int i = 0; i < 4; ++i) {
      int rb = wr + i * 16 + lq * 4;
#pragma unroll
      for (int p = 0; p < 4; ++p) {
        int r = rb + p;
        if (r < vr) {
          float* orow = ob + (size_t)(r0 + rowbase + r) * DDIM + colbase;
#pragma unroll
          for (int j = 0; j < 4; ++j) {
            int col = wc + j * 16 + l15;
            orow[col] = acc[i][j][p] + (split == 0 ? bp[col] : 0.f);
          }
        }
      }
    }
  }
}

// ---------------- K5: gated combine (splits + experts), writes y fully ----------------
__global__ __launch_bounds__(256) void combine_kernel(
    const float* __restrict__ outbuf, const int* __restrict__ posmap,
    const float* __restrict__ slotgate, float* __restrict__ y)
{
  int s = blockIdx.x;
  int tid = threadIdx.x;
  float a0 = 0.f, a1 = 0.f, a2 = 0.f;
#pragma unroll
  for (int e = 0; e < NEXP; ++e) {
    int p = posmap[e * S_TOK + s];
    if (p >= 0) {
      float g = slotgate[p];
      const float* o0 = outbuf + (size_t)p * DDIM;
      const float* o1 = outbuf + ((size_t)KSEL + p) * DDIM;
      a0 += g * (o0[tid] + o1[tid]);
      a1 += g * (o0[tid + 256] + o1[tid + 256]);
      a2 += g * (o0[tid + 512] + o1[tid + 512]);
    }
  }
  float* yr = y + (size_t)s * DDIM;
  yr[tid] = a0;
  yr[tid + 256] = a1;
  yr[tid + 512] = a2;
}

extern "C" void kernel_launch(void* const* d_in, const int* in_sizes, int n_in,
                              void* d_out, int out_size, void* d_ws, size_t ws_size,
                              hipStream_t stream) {
  const float* x  = (const float*)d_in[0];
  const float* gw = (const float*)d_in[1];
  const float* w1 = (const float*)d_in[2];
  const float* b1 = (const float*)d_in[3];
  const float* w2 = (const float*)d_in[4];
  const float* b2 = (const float*)d_in[5];
  float* y = (float*)d_out;

  char* ws = (char*)d_ws;
  float* scores    = (float*)(ws);                    // 64 KB
  int*   tokenlist = (int*)(ws + (64 << 10));         // 16 KB
  float* slotgate  = (float*)(ws + (80 << 10));       // 16 KB
  int*   offsets   = (int*)(ws + (96 << 10));         // 9 ints
  int*   posmap    = (int*)(ws + (128 << 10));        // 64 KB
  short* xbf       = (short*)(ws + (192 << 10));      // 3 MB
  short* hbuf      = (short*)(ws + (192 << 10) + (size_t)S_TOK * DDIM * 2);          // 24 MB
  float* outbuf    = (float*)(ws + (192 << 10) + (size_t)S_TOK * DDIM * 2
                                  + (size_t)KSEL * HDIM * 2);                        // 25.2 MB

  convx_kernel<<<S_TOK * DDIM / 2048, 256, 0, stream>>>(x, xbf);
  gate_kernel<<<S_TOK / 4, 256, 0, stream>>>(x, gw, scores);
  select_kernel<<<1, 1024, 0, stream>>>(scores, tokenlist, slotgate, offsets, posmap);

  dim3 g1(NEXP, HDIM / 128, 16);   // expert fastest -> id%8 == expert (XCD affinity)
  moe_mfma<1><<<g1, 256, 0, stream>>>(xbf, w1, b1, hbuf, offsets, tokenlist);
  dim3 g2(NEXP, DDIM / 128, 32);   // z = tile*2 + ksplit
  moe_mfma<2><<<g2, 256, 0, stream>>>(hbuf, w2, b2, outbuf, offsets, tokenlist);

  combine_kernel<<<S_TOK, 256, 0, stream>>>(outbuf, posmap, slotgate, y);
}